// Round 15
// baseline (189.525 us; speedup 1.0000x reference)
//
#include <hip/hip_runtime.h>

// ---------------- problem constants ----------------
#define F2      254
#define NPIX    (F2 * F2)        // 64516 conv2 output pixels
#define NANCH   (NPIX * 9)       // 580644 anchors
#define KGT     16
#define GWC     (1.0f / 1024.0f) // gw == gh == 1/IMG
#define LOSS_BLOCKS (9 * 253)    // type-major loss grid

typedef __attribute__((ext_vector_type(8))) short bf16x8;
typedef __attribute__((ext_vector_type(4))) float f32x4;

// ---------------- static device storage ----------------
__device__ unsigned short g_feats[256 * 256 * 128];  // conv1 out, bf16, 16.78 MB
__device__ unsigned short g_cls[NPIX * 9];           // cls logits bf16
__device__ unsigned short g_reg[NPIX * 36];          // reg preds bf16
__device__ unsigned short g_W2s[36 * 3 * 64 * 8];    // combined conv2 weights, bf16, MFMA-B swizzled
__device__ unsigned short g_Wbs[2 * 8 * 64 * 8];     // conv1 weights, bf16, MFMA-B swizzled (K pad 48->64)
__device__ float          g_b2[48];
__device__ float          g_acc[4];                  // bce_sum, sel_cnt, box_sum, pos_cnt
__device__ unsigned       g_keys[KGT];               // monotone-encoded gt-max
__device__ unsigned       g_done;                    // loss completion counter

__device__ __forceinline__ float b2f(unsigned short h) {
    return __uint_as_float(((unsigned)h) << 16);
}
__device__ __forceinline__ unsigned short f2b(float f) {
    unsigned u = __float_as_uint(f);
    unsigned r = (u + 0x7FFFu + ((u >> 16) & 1u)) >> 16;
    return (unsigned short)r;
}

// ---------------- shared IoU16: ONE inlined expression tree -> bit-exact across callers ----------------
__device__ __forceinline__ void iou16(float x1, float y1, float x2, float y2,
                                      const float* __restrict__ gt, float* __restrict__ v) {
    float s1 = (x2 - x1 + GWC) * (y2 - y1 + GWC);
#pragma unroll
    for (int k = 0; k < KGT; ++k) {
        float gx1 = gt[k * 4 + 0], gy1 = gt[k * 4 + 1];
        float gx2 = gt[k * 4 + 2], gy2 = gt[k * 4 + 3];
        float s2 = (gx2 - gx1 + GWC) * (gy2 - gy1 + GWC);
        float xa = fmaxf(x1, gx1), ya = fmaxf(y1, gy1);
        float xb = fminf(x2, gx2), yb = fminf(y2, gy2);
        float iw = fmaxf(xb - xa + GWC, 0.0f);
        float ih = fmaxf(yb - ya + GWC, 0.0f);
        float inter = iw * ih;
        v[k] = inter / (s1 + s2 - inter);
    }
}

// per-type half extents (uniform within a type-major block)
__device__ __forceinline__ void type_extent(int a, float* hw, float* hh) {
    int ri = a / 3, si = a - ri * 3;
    float rat = (ri == 0) ? 0.5f : (ri == 1) ? 1.0f : 2.0f;
    float scl = (si == 0) ? 0.2f : (si == 1) ? 0.4f : 0.7f;
    float rs = sqrtf(rat);
    *hw = scl * rs * 0.5f;
    *hh = scl / rs * 0.5f;
}

// ---------------- W2/Wb precombine + swizzle (+ merged init) ----------------
// blocks 0..287: combined conv2 weights (LDS-staged Wcr, wave-uniform Wi rows)
// blocks 288..291: conv1 Wb -> bf16 MFMA-B swizzle with K pad 48->64 (pad = 0)
__global__ __launch_bounds__(256) void k_w2(const float* __restrict__ Wi,
                                            const float* __restrict__ bi,
                                            const float* __restrict__ Wc,
                                            const float* __restrict__ bc,
                                            const float* __restrict__ Wr,
                                            const float* __restrict__ br,
                                            const float* __restrict__ Wb,
                                            unsigned* out) {
    int t = threadIdx.x;
    int b = blockIdx.x;
    if (b >= 288) {                  // Wb swizzle: 4 blocks x 256 thr x 8 entries
        int e = (b - 288) * 256 + t; // (kt,nt,l)
        int kt = e >> 9, nt = (e >> 6) & 7, l = e & 63;
        unsigned short w8[8];
#pragma unroll
        for (int j = 0; j < 8; ++j) {
            int k = kt * 32 + ((l >> 4) * 8) + j;
            int oc = nt * 16 + (l & 15);
            w8[j] = (k < 48) ? f2b(Wb[(size_t)k * 128 + oc]) : (unsigned short)0;
        }
        *(ulonglong2*)(g_Wbs + (size_t)e * 8) = *(ulonglong2*)w8;
        return;
    }
    __shared__ float wcr[256][48];   // 48 KB
    if (b == 0) {                    // merged init
        if (t < 4) g_acc[t] = 0.0f;
        if (t >= 4 && t < 4 + KGT) g_keys[t - 4] = 0x407FFFFFu; // enc(-1.0f)
        if (t == 32) out[0] = 0x3F803F80u;
        if (t == 33) g_done = 0u;    // reset completion counter EVERY call
    }
    for (int i = t; i < 2304; i += 256) wcr[i / 9][i % 9] = Wc[i];
    for (int i = t; i < 9216; i += 256) wcr[i / 36][9 + i % 36] = Wr[i];
    for (int i = t; i < 768; i += 256) wcr[i / 3][45 + i % 3] = 0.0f;
    __syncthreads();

    int wave = __builtin_amdgcn_readfirstlane(t >> 6);
    int lane = t & 63;
    int k = b * 4 + wave;            // 0..1151
    int o = min(lane, 47);
    const float* wik = Wi + (size_t)k * 256;
    float acc = 0.0f;
#pragma unroll 8
    for (int oc = 0; oc < 256; ++oc)
        acc = fmaf(wik[oc], wcr[oc][o], acc);

    if (lane < 48) {
        int kt = k >> 5, r5 = k & 31, j = r5 & 7, lhi = r5 >> 3;
        int nt = o >> 4, llo = o & 15, l = lhi * 16 + llo;
        g_W2s[(size_t)((kt * 3 + nt) * 64 + l) * 8 + j] = f2b(acc);
    }
    if (b == 0 && t < 48) {
        float a2 = (t < 9) ? bc[t] : ((t < 45) ? br[t - 9] : 0.0f);
        for (int oc = 0; oc < 256; ++oc) a2 = fmaf(bi[oc], wcr[oc][t], a2);
        g_b2[t] = a2;
    }
}

// helper: load 8 consecutive im2col k-values (k-order = r*12+q) of one pixel as bf16x8
__device__ __forceinline__ bf16x8 ld_a8(const float* ib, int kbase) {
    int r0 = kbase / 12, q0 = kbase - r0 * 12;
    unsigned short a8[8];
    // slice is two 16B-aligned float4s (q0 in {0,4,8}); second may wrap to next row
    float4 f0 = *(const float4*)(ib + (size_t)r0 * 3072 + q0);
    int k4 = kbase + 4;
    int r1 = k4 / 12, q1 = k4 - r1 * 12;
    float4 f1 = *(const float4*)(ib + (size_t)r1 * 3072 + q1);
    a8[0] = f2b(f0.x); a8[1] = f2b(f0.y); a8[2] = f2b(f0.z); a8[3] = f2b(f0.w);
    a8[4] = f2b(f1.x); a8[5] = f2b(f1.y); a8[6] = f2b(f1.z); a8[7] = f2b(f1.w);
    return *(bf16x8*)a8;
}

// ---------------- MERGED conv1(MFMA) + gtmax (independent work, blockIdx split) ----------------
// blocks 0..1023: conv1 GEMM M=65536,K=48(pad64),N=128; wave = 16-pixel m-tile x 128 oc
// blocks 1024..1311: gt-max, type-major with whole-wave outside skip
__global__ __launch_bounds__(256) void k_conv1gt(const float* __restrict__ img,
                                                 const float* __restrict__ bb,
                                                 const float* __restrict__ gt) {
    __shared__ float red[4][KGT];    // gtmax branch only
    int t = threadIdx.x;
    if (blockIdx.x < 1024) {
        // ---- conv1 via MFMA ----
        int l = t & 63;
        int quad = l >> 4;
        int tile = blockIdx.x * 4 + (t >> 6);   // 0..4095
        int m0 = tile * 16;
        int p = m0 + (l & 15);                  // this lane's A pixel (< 65536 always)
        int oy = p >> 8, ox = p & 255;
        const float* ib = img + ((size_t)oy * 4 * 1024 + (size_t)ox * 4) * 3;

        // A fragments: k-half 0 -> k = quad*8..+8 ; k-half 1 -> k = 32+quad*8 (quads 2,3 are pad=0)
        bf16x8 a0 = ld_a8(ib, quad * 8);
        bf16x8 a1 = (quad < 2) ? ld_a8(ib, 32 + quad * 8) : (bf16x8){0, 0, 0, 0, 0, 0, 0, 0};

        f32x4 acc[8];
#pragma unroll
        for (int nt = 0; nt < 8; ++nt) acc[nt] = (f32x4){0.0f, 0.0f, 0.0f, 0.0f};
#pragma unroll
        for (int nt = 0; nt < 8; ++nt) {
            bf16x8 b0 = *(const bf16x8*)(g_Wbs + (size_t)(nt * 64 + l) * 8);
            bf16x8 b1 = *(const bf16x8*)(g_Wbs + (size_t)((8 + nt) * 64 + l) * 8);
            acc[nt] = __builtin_amdgcn_mfma_f32_16x16x32_bf16(a0, b0, acc[nt], 0, 0, 0);
            acc[nt] = __builtin_amdgcn_mfma_f32_16x16x32_bf16(a1, b1, acc[nt], 0, 0, 0);
        }

        int n0 = l & 15;
        int mB = m0 + quad * 4;
#pragma unroll
        for (int nt = 0; nt < 8; ++nt) {
            int oc = nt * 16 + n0;
            float bias = bb[oc];
#pragma unroll
            for (int r = 0; r < 4; ++r) {
                g_feats[(size_t)(mB + r) * 128 + oc] = f2b(acc[nt][r] + bias);
            }
        }
    } else {
        // ---- gtmax ----
        int bid = blockIdx.x - 1024;
        int a = bid >> 5;             // 0..8
        int blk = bid & 31;
        float hw, hh;
        type_extent(a, &hw, &hh);
        float m16[KGT];
#pragma unroll
        for (int k = 0; k < KGT; ++k) m16[k] = -1.0f;
        for (int pix = blk * 256 + t; pix < NPIX; pix += 32 * 256) {
            int w = pix / F2, h = pix - w * F2;
            float cx = (float)w * (1.0f / 254.0f);
            float cy = (float)h * (1.0f / 254.0f);
            float x1 = cx - hw, y1 = cy - hh, x2 = cx + hw, y2 = cy + hh;
            bool inside = (x1 >= 0.0f) && (y1 >= 0.0f) && (x2 < 1.0f) && (y2 < 1.0f);
            if (__ballot(inside) == 0ull) continue;   // whole wave outside
            if (inside) {
                float v[KGT];
                iou16(x1, y1, x2, y2, gt, v);
#pragma unroll
                for (int k = 0; k < KGT; ++k) m16[k] = fmaxf(m16[k], v[k]);
            }
        }
#pragma unroll
        for (int k = 0; k < KGT; ++k) {
#pragma unroll
            for (int m = 32; m; m >>= 1) m16[k] = fmaxf(m16[k], __shfl_xor(m16[k], m, 64));
        }
        int lane = t & 63, wv = t >> 6;
        if (lane == 0) {
#pragma unroll
            for (int k = 0; k < KGT; ++k) red[wv][k] = m16[k];
        }
        __syncthreads();
        if (t < KGT) {
            float mx = fmaxf(fmaxf(red[0][t], red[1][t]), fmaxf(red[2][t], red[3][t]));
            unsigned u = __float_as_uint(mx);
            unsigned key = (u & 0x80000000u) ? ~u : (u | 0x80000000u);
            atomicMax(&g_keys[t], key);
        }
    }
}

// ---------------- combined conv via MFMA, 4 M-tiles/wave (B shared across all 4) ----------------
__global__ __launch_bounds__(256) void k_convC() {
    int t = threadIdx.x;
    int l = t & 63;
    int quad = l >> 4;
    int tile = blockIdx.x * 4 + (t >> 6);
    int m0 = tile * 64;
    int py[4], px[4];
#pragma unroll
    for (int h = 0; h < 4; ++h) {
        int mA = min(m0 + h * 16 + (l & 15), NPIX - 1);
        py[h] = mA / F2; px[h] = mA - py[h] * F2;
    }

    f32x4 acc[4][3];
#pragma unroll
    for (int h = 0; h < 4; ++h)
#pragma unroll
        for (int nt = 0; nt < 3; ++nt) acc[h][nt] = (f32x4){0.0f, 0.0f, 0.0f, 0.0f};

    int kt = 0;
#pragma unroll
    for (int ky = 0; ky < 3; ++ky) {
#pragma unroll
        for (int kx = 0; kx < 3; ++kx) {
#pragma unroll
            for (int kc = 0; kc < 4; ++kc) {
                const unsigned short* bp = g_W2s + (size_t)kt * 1536 + l * 8;
                bf16x8 b0 = *(const bf16x8*)(bp);
                bf16x8 b1 = *(const bf16x8*)(bp + 512);
                bf16x8 b2v = *(const bf16x8*)(bp + 1024);
#pragma unroll
                for (int h = 0; h < 4; ++h) {
                    const unsigned short* ap =
                        g_feats + ((size_t)(py[h] + ky) * 256 + (px[h] + kx)) * 128 + quad * 8;
                    bf16x8 a = *(const bf16x8*)(ap + kc * 32);
                    acc[h][0] = __builtin_amdgcn_mfma_f32_16x16x32_bf16(a, b0, acc[h][0], 0, 0, 0);
                    acc[h][1] = __builtin_amdgcn_mfma_f32_16x16x32_bf16(a, b1, acc[h][1], 0, 0, 0);
                    acc[h][2] = __builtin_amdgcn_mfma_f32_16x16x32_bf16(a, b2v, acc[h][2], 0, 0, 0);
                }
                ++kt;
            }
        }
    }

    int n0 = l & 15;
#pragma unroll
    for (int h = 0; h < 4; ++h) {
        int mB = m0 + h * 16 + quad * 4;
#pragma unroll
        for (int nt = 0; nt < 3; ++nt) {
            int n = nt * 16 + n0;
            if (n >= 45) continue;
            float bias = g_b2[n];
#pragma unroll
            for (int r = 0; r < 4; ++r) {
                int m = mB + r;
                if (m < NPIX) {
                    float vv = acc[h][nt][r] + bias;
                    if (n < 9) g_cls[(size_t)m * 9 + n] = f2b(vv);
                    else       g_reg[(size_t)m * 36 + (n - 9)] = f2b(vv);
                }
            }
        }
    }
}

// ---------------- loss, TYPE-MAJOR + merged finalize via counter (NO per-block fence) ----------------
__global__ __launch_bounds__(256) void k_loss(const float* __restrict__ gt, unsigned* out) {
    __shared__ float red[4][4];
    int t = threadIdx.x;
    int a = blockIdx.x / 253;         // 0..8
    int pix = (blockIdx.x - a * 253) * 256 + t;
    float sb = 0.0f, ss = 0.0f, sx = 0.0f, sp = 0.0f;
    float hw, hh;
    type_extent(a, &hw, &hh);
    bool inside = false;
    float x1, y1, x2, y2;
    if (pix < NPIX) {
        int w = pix / F2, h = pix - w * F2;
        float cx = (float)w * (1.0f / 254.0f);
        float cy = (float)h * (1.0f / 254.0f);
        x1 = cx - hw; y1 = cy - hh; x2 = cx + hw; y2 = cy + hh;
        inside = (x1 >= 0.0f) && (y1 >= 0.0f) && (x2 < 1.0f) && (y2 < 1.0f);
    }
    if (__ballot(inside) != 0ull) {
        if (inside) {
            int n = pix * 9 + a;
            float v[KGT];
            iou16(x1, y1, x2, y2, gt, v);
            float maxi = -1.0f;
            bool best = false;
#pragma unroll
            for (int k = 0; k < KGT; ++k) {
                maxi = fmaxf(maxi, v[k]);
                unsigned e = g_keys[k];
                float gm = __uint_as_float((e & 0x80000000u) ? (e & 0x7FFFFFFFu) : ~e);
                best = best || (v[k] == gm);
            }
            bool ispos = best || (maxi >= 0.5f);
            float c = b2f(g_cls[n]);
            float z = ispos ? -c : c;
            sb = fmaxf(z, 0.0f) + log1pf(expf(-fabsf(z))); // softplus(z)
            ss = 1.0f;
            if (ispos) {
                ushort4 rh = *(const ushort4*)(g_reg + (size_t)n * 4);
                float aa;
                aa = fabsf(b2f(rh.x)); sx += (aa < 1.0f) ? 0.5f * aa * aa : aa - 0.5f;
                aa = fabsf(b2f(rh.y)); sx += (aa < 1.0f) ? 0.5f * aa * aa : aa - 0.5f;
                aa = fabsf(b2f(rh.z)); sx += (aa < 1.0f) ? 0.5f * aa * aa : aa - 0.5f;
                aa = fabsf(b2f(rh.w)); sx += (aa < 1.0f) ? 0.5f * aa * aa : aa - 0.5f;
                sp = 1.0f;
            }
        }
    }
#pragma unroll
    for (int m = 32; m; m >>= 1) {
        sb += __shfl_xor(sb, m, 64);
        ss += __shfl_xor(ss, m, 64);
        sx += __shfl_xor(sx, m, 64);
        sp += __shfl_xor(sp, m, 64);
    }
    int lane = t & 63, wv = t >> 6;
    if (lane == 0) { red[wv][0] = sb; red[wv][1] = ss; red[wv][2] = sx; red[wv][3] = sp; }
    __syncthreads();
    if (t < 4) {
        float s = red[0][t] + red[1][t] + red[2][t] + red[3][t];
        atomicAdd(&g_acc[t], s);
    }
    // barrier drains vmcnt -> this block's g_acc atomics are L2-visible before g_done bump
    __syncthreads();
    if (t == 0) {
        unsigned prev = atomicAdd(&g_done, 1u);
        if (prev == LOSS_BLOCKS - 1) {   // last block finalizes; atomics read L2 truth
            float a0 = atomicAdd(&g_acc[0], 0.0f);
            float a1 = atomicAdd(&g_acc[1], 0.0f);
            float a2 = atomicAdd(&g_acc[2], 0.0f);
            float a3 = atomicAdd(&g_acc[3], 0.0f);
            float res = a0 / a1 + a2 / a3;
            unsigned lo = (unsigned)f2b(res);
            unsigned hi = __float_as_uint(res) >> 16;
            out[0] = (hi << 16) | lo;
        }
    }
}

extern "C" void kernel_launch(void* const* d_in, const int* in_sizes, int n_in,
                              void* d_out, int out_size, void* d_ws, size_t ws_size,
                              hipStream_t stream) {
    (void)in_sizes; (void)n_in; (void)out_size; (void)d_ws; (void)ws_size;
    const float* image = (const float*)d_in[0];
    const float* gt    = (const float*)d_in[1];
    const float* Wb    = (const float*)d_in[2];
    const float* bb    = (const float*)d_in[3];
    const float* Wi    = (const float*)d_in[4];
    const float* bi    = (const float*)d_in[5];
    const float* Wc    = (const float*)d_in[6];
    const float* bc    = (const float*)d_in[7];
    const float* Wr    = (const float*)d_in[8];
    const float* br    = (const float*)d_in[9];

    k_w2     <<<292, 256, 0, stream>>>(Wi, bi, Wc, bc, Wr, br, Wb, (unsigned*)d_out);
    k_conv1gt<<<1312, 256, 0, stream>>>(image, bb, gt);
    k_convC  <<<253, 256, 0, stream>>>();
    k_loss   <<<LOSS_BLOCKS, 256, 0, stream>>>(gt, (unsigned*)d_out);
}

// Round 16
// 174.972 us; speedup vs baseline: 1.0832x; 1.0832x over previous
//
#include <hip/hip_runtime.h>

// ---------------- problem constants ----------------
#define F2      254
#define NPIX    (F2 * F2)        // 64516 conv2 output pixels
#define NANCH   (NPIX * 9)       // 580644 anchors
#define KGT     16
#define GWC     (1.0f / 1024.0f) // gw == gh == 1/IMG
#define LOSS_BLOCKS (9 * 253)    // type-major loss grid

typedef __attribute__((ext_vector_type(8))) short bf16x8;
typedef __attribute__((ext_vector_type(4))) float f32x4;

// ---------------- static device storage ----------------
__device__ unsigned short g_feats[256 * 256 * 128];  // conv1 out, bf16, 16.78 MB
__device__ unsigned short g_cls[NPIX * 9];           // cls logits bf16
__device__ unsigned short g_reg[NPIX * 36];          // reg preds bf16
__device__ unsigned short g_W2s[36 * 3 * 64 * 8];    // combined conv2 weights, bf16, MFMA-B swizzled
__device__ unsigned short g_Wbs[2 * 8 * 64 * 8];     // conv1 weights, bf16, MFMA-B swizzled (K pad 48->64)
__device__ float          g_b2[48];
__device__ float          g_acc[4];                  // bce_sum, sel_cnt, box_sum, pos_cnt
__device__ unsigned       g_keys[KGT];               // monotone-encoded gt-max
__device__ unsigned       g_done;                    // loss completion counter

__device__ __forceinline__ float b2f(unsigned short h) {
    return __uint_as_float(((unsigned)h) << 16);
}
__device__ __forceinline__ unsigned short f2b(float f) {
    unsigned u = __float_as_uint(f);
    unsigned r = (u + 0x7FFFu + ((u >> 16) & 1u)) >> 16;
    return (unsigned short)r;
}

// ---------------- shared IoU16: ONE inlined expression tree -> bit-exact across callers ----------------
__device__ __forceinline__ void iou16(float x1, float y1, float x2, float y2,
                                      const float* __restrict__ gt, float* __restrict__ v) {
    float s1 = (x2 - x1 + GWC) * (y2 - y1 + GWC);
#pragma unroll
    for (int k = 0; k < KGT; ++k) {
        float gx1 = gt[k * 4 + 0], gy1 = gt[k * 4 + 1];
        float gx2 = gt[k * 4 + 2], gy2 = gt[k * 4 + 3];
        float s2 = (gx2 - gx1 + GWC) * (gy2 - gy1 + GWC);
        float xa = fmaxf(x1, gx1), ya = fmaxf(y1, gy1);
        float xb = fminf(x2, gx2), yb = fminf(y2, gy2);
        float iw = fmaxf(xb - xa + GWC, 0.0f);
        float ih = fmaxf(yb - ya + GWC, 0.0f);
        float inter = iw * ih;
        v[k] = inter / (s1 + s2 - inter);
    }
}

// per-type half extents (uniform within a type-major block)
__device__ __forceinline__ void type_extent(int a, float* hw, float* hh) {
    int ri = a / 3, si = a - ri * 3;
    float rat = (ri == 0) ? 0.5f : (ri == 1) ? 1.0f : 2.0f;
    float scl = (si == 0) ? 0.2f : (si == 1) ? 0.4f : 0.7f;
    float rs = sqrtf(rat);
    *hw = scl * rs * 0.5f;
    *hh = scl / rs * 0.5f;
}

// ---------------- W2/Wb precombine + swizzle (+ merged init) ----------------
__global__ __launch_bounds__(256) void k_w2(const float* __restrict__ Wi,
                                            const float* __restrict__ bi,
                                            const float* __restrict__ Wc,
                                            const float* __restrict__ bc,
                                            const float* __restrict__ Wr,
                                            const float* __restrict__ br,
                                            const float* __restrict__ Wb,
                                            unsigned* out) {
    int t = threadIdx.x;
    int b = blockIdx.x;
    if (b >= 288) {                  // Wb swizzle: 4 blocks x 256 thr x 8 entries
        int e = (b - 288) * 256 + t; // (kt,nt,l)
        int kt = e >> 9, nt = (e >> 6) & 7, l = e & 63;
        unsigned short w8[8];
#pragma unroll
        for (int j = 0; j < 8; ++j) {
            int k = kt * 32 + ((l >> 4) * 8) + j;
            int oc = nt * 16 + (l & 15);
            w8[j] = (k < 48) ? f2b(Wb[(size_t)k * 128 + oc]) : (unsigned short)0;
        }
        *(ulonglong2*)(g_Wbs + (size_t)e * 8) = *(ulonglong2*)w8;
        return;
    }
    __shared__ float wcr[256][48];   // 48 KB
    if (b == 0) {                    // merged init
        if (t < 4) g_acc[t] = 0.0f;
        if (t >= 4 && t < 4 + KGT) g_keys[t - 4] = 0x407FFFFFu; // enc(-1.0f)
        if (t == 32) out[0] = 0x3F803F80u;
        if (t == 33) g_done = 0u;    // reset completion counter EVERY call
    }
    for (int i = t; i < 2304; i += 256) wcr[i / 9][i % 9] = Wc[i];
    for (int i = t; i < 9216; i += 256) wcr[i / 36][9 + i % 36] = Wr[i];
    for (int i = t; i < 768; i += 256) wcr[i / 3][45 + i % 3] = 0.0f;
    __syncthreads();

    int wave = __builtin_amdgcn_readfirstlane(t >> 6);
    int lane = t & 63;
    int k = b * 4 + wave;            // 0..1151
    int o = min(lane, 47);
    const float* wik = Wi + (size_t)k * 256;
    float acc = 0.0f;
#pragma unroll 8
    for (int oc = 0; oc < 256; ++oc)
        acc = fmaf(wik[oc], wcr[oc][o], acc);

    if (lane < 48) {
        int kt = k >> 5, r5 = k & 31, j = r5 & 7, lhi = r5 >> 3;
        int nt = o >> 4, llo = o & 15, l = lhi * 16 + llo;
        g_W2s[(size_t)((kt * 3 + nt) * 64 + l) * 8 + j] = f2b(acc);
    }
    if (b == 0 && t < 48) {
        float a2 = (t < 9) ? bc[t] : ((t < 45) ? br[t - 9] : 0.0f);
        for (int oc = 0; oc < 256; ++oc) a2 = fmaf(bi[oc], wcr[oc][t], a2);
        g_b2[t] = a2;
    }
}

// helper: load 8 consecutive im2col k-values (k-order = r*12+q) of one pixel as bf16x8
__device__ __forceinline__ bf16x8 ld_a8(const float* ib, int kbase) {
    int r0 = kbase / 12, q0 = kbase - r0 * 12;
    unsigned short a8[8];
    float4 f0 = *(const float4*)(ib + (size_t)r0 * 3072 + q0);
    int k4 = kbase + 4;
    int r1 = k4 / 12, q1 = k4 - r1 * 12;
    float4 f1 = *(const float4*)(ib + (size_t)r1 * 3072 + q1);
    a8[0] = f2b(f0.x); a8[1] = f2b(f0.y); a8[2] = f2b(f0.z); a8[3] = f2b(f0.w);
    a8[4] = f2b(f1.x); a8[5] = f2b(f1.y); a8[6] = f2b(f1.z); a8[7] = f2b(f1.w);
    return *(bf16x8*)a8;
}

// ---------------- MERGED conv1(MFMA) + gtmax (independent work, blockIdx split) ----------------
__global__ __launch_bounds__(256) void k_conv1gt(const float* __restrict__ img,
                                                 const float* __restrict__ bb,
                                                 const float* __restrict__ gt) {
    __shared__ float red[4][KGT];    // gtmax branch only
    int t = threadIdx.x;
    if (blockIdx.x < 1024) {
        // ---- conv1 via MFMA: GEMM M=65536, K=48(pad64), N=128 ----
        int l = t & 63;
        int quad = l >> 4;
        int tile = blockIdx.x * 4 + (t >> 6);   // 0..4095
        int m0 = tile * 16;
        int p = m0 + (l & 15);
        int oy = p >> 8, ox = p & 255;
        const float* ib = img + ((size_t)oy * 4 * 1024 + (size_t)ox * 4) * 3;

        bf16x8 a0 = ld_a8(ib, quad * 8);
        bf16x8 a1 = (quad < 2) ? ld_a8(ib, 32 + quad * 8) : (bf16x8){0, 0, 0, 0, 0, 0, 0, 0};

        f32x4 acc[8];
#pragma unroll
        for (int nt = 0; nt < 8; ++nt) acc[nt] = (f32x4){0.0f, 0.0f, 0.0f, 0.0f};
#pragma unroll
        for (int nt = 0; nt < 8; ++nt) {
            bf16x8 b0 = *(const bf16x8*)(g_Wbs + (size_t)(nt * 64 + l) * 8);
            bf16x8 b1 = *(const bf16x8*)(g_Wbs + (size_t)((8 + nt) * 64 + l) * 8);
            acc[nt] = __builtin_amdgcn_mfma_f32_16x16x32_bf16(a0, b0, acc[nt], 0, 0, 0);
            acc[nt] = __builtin_amdgcn_mfma_f32_16x16x32_bf16(a1, b1, acc[nt], 0, 0, 0);
        }

        int n0 = l & 15;
        int mB = m0 + quad * 4;
#pragma unroll
        for (int nt = 0; nt < 8; ++nt) {
            int oc = nt * 16 + n0;
            float bias = bb[oc];
#pragma unroll
            for (int r = 0; r < 4; ++r) {
                g_feats[(size_t)(mB + r) * 128 + oc] = f2b(acc[nt][r] + bias);
            }
        }
    } else {
        // ---- gtmax ----
        int bid = blockIdx.x - 1024;
        int a = bid >> 5;             // 0..8
        int blk = bid & 31;
        float hw, hh;
        type_extent(a, &hw, &hh);
        float m16[KGT];
#pragma unroll
        for (int k = 0; k < KGT; ++k) m16[k] = -1.0f;
        for (int pix = blk * 256 + t; pix < NPIX; pix += 32 * 256) {
            int w = pix / F2, h = pix - w * F2;
            float cx = (float)w * (1.0f / 254.0f);
            float cy = (float)h * (1.0f / 254.0f);
            float x1 = cx - hw, y1 = cy - hh, x2 = cx + hw, y2 = cy + hh;
            bool inside = (x1 >= 0.0f) && (y1 >= 0.0f) && (x2 < 1.0f) && (y2 < 1.0f);
            if (__ballot(inside) == 0ull) continue;   // whole wave outside
            if (inside) {
                float v[KGT];
                iou16(x1, y1, x2, y2, gt, v);
#pragma unroll
                for (int k = 0; k < KGT; ++k) m16[k] = fmaxf(m16[k], v[k]);
            }
        }
#pragma unroll
        for (int k = 0; k < KGT; ++k) {
#pragma unroll
            for (int m = 32; m; m >>= 1) m16[k] = fmaxf(m16[k], __shfl_xor(m16[k], m, 64));
        }
        int lane = t & 63, wv = t >> 6;
        if (lane == 0) {
#pragma unroll
            for (int k = 0; k < KGT; ++k) red[wv][k] = m16[k];
        }
        __syncthreads();
        if (t < KGT) {
            float mx = fmaxf(fmaxf(red[0][t], red[1][t]), fmaxf(red[2][t], red[3][t]));
            unsigned u = __float_as_uint(mx);
            unsigned key = (u & 0x80000000u) ? ~u : (u | 0x80000000u);
            atomicMax(&g_keys[t], key);
        }
    }
}

// ---------------- combined conv via MFMA, 2 M-tiles/wave (r14 proven shape, 505 blocks) ----------------
__global__ __launch_bounds__(256) void k_convC() {
    int t = threadIdx.x;
    int l = t & 63;
    int quad = l >> 4;
    int tile = blockIdx.x * 4 + (t >> 6);
    int m0 = tile * 32;
    int mA0 = min(m0 + (l & 15), NPIX - 1);
    int mA1 = min(m0 + 16 + (l & 15), NPIX - 1);
    int py0 = mA0 / F2, px0 = mA0 - py0 * F2;
    int py1 = mA1 / F2, px1 = mA1 - py1 * F2;

    f32x4 acc[2][3];
#pragma unroll
    for (int h = 0; h < 2; ++h)
#pragma unroll
        for (int nt = 0; nt < 3; ++nt) acc[h][nt] = (f32x4){0.0f, 0.0f, 0.0f, 0.0f};

    int kt = 0;
#pragma unroll
    for (int ky = 0; ky < 3; ++ky) {
#pragma unroll
        for (int kx = 0; kx < 3; ++kx) {
            const unsigned short* ap0 =
                g_feats + ((size_t)(py0 + ky) * 256 + (px0 + kx)) * 128 + quad * 8;
            const unsigned short* ap1 =
                g_feats + ((size_t)(py1 + ky) * 256 + (px1 + kx)) * 128 + quad * 8;
#pragma unroll
            for (int kc = 0; kc < 4; ++kc) {
                bf16x8 a0 = *(const bf16x8*)(ap0 + kc * 32);
                bf16x8 a1 = *(const bf16x8*)(ap1 + kc * 32);
                const unsigned short* bp = g_W2s + (size_t)kt * 1536 + l * 8;
                bf16x8 b0 = *(const bf16x8*)(bp);
                bf16x8 b1 = *(const bf16x8*)(bp + 512);
                bf16x8 b2v = *(const bf16x8*)(bp + 1024);
                acc[0][0] = __builtin_amdgcn_mfma_f32_16x16x32_bf16(a0, b0, acc[0][0], 0, 0, 0);
                acc[0][1] = __builtin_amdgcn_mfma_f32_16x16x32_bf16(a0, b1, acc[0][1], 0, 0, 0);
                acc[0][2] = __builtin_amdgcn_mfma_f32_16x16x32_bf16(a0, b2v, acc[0][2], 0, 0, 0);
                acc[1][0] = __builtin_amdgcn_mfma_f32_16x16x32_bf16(a1, b0, acc[1][0], 0, 0, 0);
                acc[1][1] = __builtin_amdgcn_mfma_f32_16x16x32_bf16(a1, b1, acc[1][1], 0, 0, 0);
                acc[1][2] = __builtin_amdgcn_mfma_f32_16x16x32_bf16(a1, b2v, acc[1][2], 0, 0, 0);
                ++kt;
            }
        }
    }

    int n0 = l & 15;
#pragma unroll
    for (int h = 0; h < 2; ++h) {
        int mB = m0 + h * 16 + quad * 4;
#pragma unroll
        for (int nt = 0; nt < 3; ++nt) {
            int n = nt * 16 + n0;
            if (n >= 45) continue;
            float bias = g_b2[n];
#pragma unroll
            for (int r = 0; r < 4; ++r) {
                int m = mB + r;
                if (m < NPIX) {
                    float vv = acc[h][nt][r] + bias;
                    if (n < 9) g_cls[(size_t)m * 9 + n] = f2b(vv);
                    else       g_reg[(size_t)m * 36 + (n - 9)] = f2b(vv);
                }
            }
        }
    }
}

// ---------------- loss, TYPE-MAJOR + merged finalize via counter (NO per-block fence) ----------------
__global__ __launch_bounds__(256) void k_loss(const float* __restrict__ gt, unsigned* out) {
    __shared__ float red[4][4];
    int t = threadIdx.x;
    int a = blockIdx.x / 253;         // 0..8
    int pix = (blockIdx.x - a * 253) * 256 + t;
    float sb = 0.0f, ss = 0.0f, sx = 0.0f, sp = 0.0f;
    float hw, hh;
    type_extent(a, &hw, &hh);
    bool inside = false;
    float x1, y1, x2, y2;
    if (pix < NPIX) {
        int w = pix / F2, h = pix - w * F2;
        float cx = (float)w * (1.0f / 254.0f);
        float cy = (float)h * (1.0f / 254.0f);
        x1 = cx - hw; y1 = cy - hh; x2 = cx + hw; y2 = cy + hh;
        inside = (x1 >= 0.0f) && (y1 >= 0.0f) && (x2 < 1.0f) && (y2 < 1.0f);
    }
    if (__ballot(inside) != 0ull) {
        if (inside) {
            int n = pix * 9 + a;
            float v[KGT];
            iou16(x1, y1, x2, y2, gt, v);
            float maxi = -1.0f;
            bool best = false;
#pragma unroll
            for (int k = 0; k < KGT; ++k) {
                maxi = fmaxf(maxi, v[k]);
                unsigned e = g_keys[k];
                float gm = __uint_as_float((e & 0x80000000u) ? (e & 0x7FFFFFFFu) : ~e);
                best = best || (v[k] == gm);
            }
            bool ispos = best || (maxi >= 0.5f);
            float c = b2f(g_cls[n]);
            float z = ispos ? -c : c;
            sb = fmaxf(z, 0.0f) + log1pf(expf(-fabsf(z))); // softplus(z)
            ss = 1.0f;
            if (ispos) {
                ushort4 rh = *(const ushort4*)(g_reg + (size_t)n * 4);
                float aa;
                aa = fabsf(b2f(rh.x)); sx += (aa < 1.0f) ? 0.5f * aa * aa : aa - 0.5f;
                aa = fabsf(b2f(rh.y)); sx += (aa < 1.0f) ? 0.5f * aa * aa : aa - 0.5f;
                aa = fabsf(b2f(rh.z)); sx += (aa < 1.0f) ? 0.5f * aa * aa : aa - 0.5f;
                aa = fabsf(b2f(rh.w)); sx += (aa < 1.0f) ? 0.5f * aa * aa : aa - 0.5f;
                sp = 1.0f;
            }
        }
    }
#pragma unroll
    for (int m = 32; m; m >>= 1) {
        sb += __shfl_xor(sb, m, 64);
        ss += __shfl_xor(ss, m, 64);
        sx += __shfl_xor(sx, m, 64);
        sp += __shfl_xor(sp, m, 64);
    }
    int lane = t & 63, wv = t >> 6;
    if (lane == 0) { red[wv][0] = sb; red[wv][1] = ss; red[wv][2] = sx; red[wv][3] = sp; }
    __syncthreads();
    if (t < 4) {
        float s = red[0][t] + red[1][t] + red[2][t] + red[3][t];
        atomicAdd(&g_acc[t], s);
    }
    // barrier drains vmcnt -> this block's g_acc atomics are L2-visible before g_done bump
    __syncthreads();
    if (t == 0) {
        unsigned prev = atomicAdd(&g_done, 1u);
        if (prev == LOSS_BLOCKS - 1) {   // last block finalizes; atomics read L2 truth
            float a0 = atomicAdd(&g_acc[0], 0.0f);
            float a1 = atomicAdd(&g_acc[1], 0.0f);
            float a2 = atomicAdd(&g_acc[2], 0.0f);
            float a3 = atomicAdd(&g_acc[3], 0.0f);
            float res = a0 / a1 + a2 / a3;
            unsigned lo = (unsigned)f2b(res);
            unsigned hi = __float_as_uint(res) >> 16;
            out[0] = (hi << 16) | lo;
        }
    }
}

extern "C" void kernel_launch(void* const* d_in, const int* in_sizes, int n_in,
                              void* d_out, int out_size, void* d_ws, size_t ws_size,
                              hipStream_t stream) {
    (void)in_sizes; (void)n_in; (void)out_size; (void)d_ws; (void)ws_size;
    const float* image = (const float*)d_in[0];
    const float* gt    = (const float*)d_in[1];
    const float* Wb    = (const float*)d_in[2];
    const float* bb    = (const float*)d_in[3];
    const float* Wi    = (const float*)d_in[4];
    const float* bi    = (const float*)d_in[5];
    const float* Wc    = (const float*)d_in[6];
    const float* bc    = (const float*)d_in[7];
    const float* Wr    = (const float*)d_in[8];
    const float* br    = (const float*)d_in[9];

    k_w2     <<<292, 256, 0, stream>>>(Wi, bi, Wc, bc, Wr, br, Wb, (unsigned*)d_out);
    k_conv1gt<<<1312, 256, 0, stream>>>(image, bb, gt);
    k_convC  <<<505, 256, 0, stream>>>();
    k_loss   <<<LOSS_BLOCKS, 256, 0, stream>>>(gt, (unsigned*)d_out);
}

// Round 18
// 153.402 us; speedup vs baseline: 1.2355x; 1.1406x over previous
//
#include <hip/hip_runtime.h>

// ---------------- problem constants ----------------
#define F2      254
#define NPIX    (F2 * F2)        // 64516 conv2 output pixels
#define NANCH   (NPIX * 9)       // 580644 anchors
#define KGT     16
#define GWC     (1.0f / 1024.0f) // gw == gh == 1/IMG

typedef __attribute__((ext_vector_type(8))) short bf16x8;
typedef __attribute__((ext_vector_type(4))) float f32x4;

// loss compact-grid map (host-computed, passed by value)
struct LossMap {
    int w0[9], h0[9], hsp[9], blk0[10];
};

// ---------------- static device storage ----------------
__device__ unsigned short g_feats[256 * 256 * 128];  // conv1 out, bf16, 16.78 MB
__device__ unsigned short g_cls[NPIX * 9];           // cls logits bf16
__device__ unsigned short g_reg[NPIX * 36];          // reg preds bf16
__device__ unsigned short g_W2s[36 * 3 * 64 * 8];    // combined conv2 weights, bf16, MFMA-B swizzled
__device__ unsigned short g_Wbs[2 * 8 * 64 * 8];     // conv1 weights, bf16, MFMA-B swizzled (K pad 48->64)
__device__ float          g_b2[48];
__device__ float          g_acc[4];                  // bce_sum, sel_cnt, box_sum, pos_cnt
__device__ unsigned       g_keys[KGT];               // monotone-encoded gt-max
__device__ unsigned       g_done;                    // loss completion counter

__device__ __forceinline__ float b2f(unsigned short h) {
    return __uint_as_float(((unsigned)h) << 16);
}
__device__ __forceinline__ unsigned short f2b(float f) {
    unsigned u = __float_as_uint(f);
    unsigned r = (u + 0x7FFFu + ((u >> 16) & 1u)) >> 16;
    return (unsigned short)r;
}

// ---------------- shared IoU16: ONE inlined expression tree -> bit-exact across callers ----------------
__device__ __forceinline__ void iou16(float x1, float y1, float x2, float y2,
                                      const float* __restrict__ gt, float* __restrict__ v) {
    float s1 = (x2 - x1 + GWC) * (y2 - y1 + GWC);
#pragma unroll
    for (int k = 0; k < KGT; ++k) {
        float gx1 = gt[k * 4 + 0], gy1 = gt[k * 4 + 1];
        float gx2 = gt[k * 4 + 2], gy2 = gt[k * 4 + 3];
        float s2 = (gx2 - gx1 + GWC) * (gy2 - gy1 + GWC);
        float xa = fmaxf(x1, gx1), ya = fmaxf(y1, gy1);
        float xb = fminf(x2, gx2), yb = fminf(y2, gy2);
        float iw = fmaxf(xb - xa + GWC, 0.0f);
        float ih = fmaxf(yb - ya + GWC, 0.0f);
        float inter = iw * ih;
        v[k] = inter / (s1 + s2 - inter);
    }
}

// per-type half extents (uniform within a type-major block)
__device__ __forceinline__ void type_extent(int a, float* hw, float* hh) {
    int ri = a / 3, si = a - ri * 3;
    float rat = (ri == 0) ? 0.5f : (ri == 1) ? 1.0f : 2.0f;
    float scl = (si == 0) ? 0.2f : (si == 1) ? 0.4f : 0.7f;
    float rs = sqrtf(rat);
    *hw = scl * rs * 0.5f;
    *hh = scl / rs * 0.5f;
}

// ---------------- W2/Wb precombine + swizzle (+ merged init) — r16-proven, OWN LAUNCH ----------------
__global__ __launch_bounds__(256) void k_w2(const float* __restrict__ Wi,
                                            const float* __restrict__ bi,
                                            const float* __restrict__ Wc,
                                            const float* __restrict__ bc,
                                            const float* __restrict__ Wr,
                                            const float* __restrict__ br,
                                            const float* __restrict__ Wb,
                                            unsigned* out) {
    int t = threadIdx.x;
    int b = blockIdx.x;
    if (b >= 288) {                  // Wb swizzle: 4 blocks x 256 thr x 8 entries
        int e = (b - 288) * 256 + t; // (kt,nt,l)
        int kt = e >> 9, nt = (e >> 6) & 7, l = e & 63;
        unsigned short w8[8];
#pragma unroll
        for (int j = 0; j < 8; ++j) {
            int k = kt * 32 + ((l >> 4) * 8) + j;
            int oc = nt * 16 + (l & 15);
            w8[j] = (k < 48) ? f2b(Wb[(size_t)k * 128 + oc]) : (unsigned short)0;
        }
        *(ulonglong2*)(g_Wbs + (size_t)e * 8) = *(ulonglong2*)w8;
        return;
    }
    __shared__ float wcr[256][48];   // 48 KB
    if (b == 0) {                    // merged init (resets ALL cross-call state every call)
        if (t < 4) g_acc[t] = 0.0f;
        if (t >= 4 && t < 4 + KGT) g_keys[t - 4] = 0x407FFFFFu; // enc(-1.0f)
        if (t == 32) out[0] = 0x3F803F80u;
        if (t == 33) g_done = 0u;
    }
    for (int i = t; i < 2304; i += 256) wcr[i / 9][i % 9] = Wc[i];
    for (int i = t; i < 9216; i += 256) wcr[i / 36][9 + i % 36] = Wr[i];
    for (int i = t; i < 768; i += 256) wcr[i / 3][45 + i % 3] = 0.0f;
    __syncthreads();

    int wave = __builtin_amdgcn_readfirstlane(t >> 6);
    int lane = t & 63;
    int k = b * 4 + wave;            // 0..1151
    int o = min(lane, 47);
    const float* wik = Wi + (size_t)k * 256;
    float acc = 0.0f;
#pragma unroll 8
    for (int oc = 0; oc < 256; ++oc)
        acc = fmaf(wik[oc], wcr[oc][o], acc);

    if (lane < 48) {
        int kt = k >> 5, r5 = k & 31, j = r5 & 7, lhi = r5 >> 3;
        int nt = o >> 4, llo = o & 15, l = lhi * 16 + llo;
        g_W2s[(size_t)((kt * 3 + nt) * 64 + l) * 8 + j] = f2b(acc);
    }
    if (b == 0 && t < 48) {
        float a2 = (t < 9) ? bc[t] : ((t < 45) ? br[t - 9] : 0.0f);
        for (int oc = 0; oc < 256; ++oc) a2 = fmaf(bi[oc], wcr[oc][t], a2);
        g_b2[t] = a2;
    }
}

// helper: load 8 consecutive im2col k-values (k-order = r*12+q) of one pixel as bf16x8
__device__ __forceinline__ bf16x8 ld_a8(const float* ib, int kbase) {
    int r0 = kbase / 12, q0 = kbase - r0 * 12;
    unsigned short a8[8];
    float4 f0 = *(const float4*)(ib + (size_t)r0 * 3072 + q0);
    int k4 = kbase + 4;
    int r1 = k4 / 12, q1 = k4 - r1 * 12;
    float4 f1 = *(const float4*)(ib + (size_t)r1 * 3072 + q1);
    a8[0] = f2b(f0.x); a8[1] = f2b(f0.y); a8[2] = f2b(f0.z); a8[3] = f2b(f0.w);
    a8[4] = f2b(f1.x); a8[5] = f2b(f1.y); a8[6] = f2b(f1.z); a8[7] = f2b(f1.w);
    return *(bf16x8*)a8;
}

// ---------------- MERGED conv1(MFMA) + gtmax — consumes g_Wbs across a KERNEL BOUNDARY ----------------
__global__ __launch_bounds__(256) void k_conv1gt(const float* __restrict__ img,
                                                 const float* __restrict__ bb,
                                                 const float* __restrict__ gt) {
    __shared__ float red[4][KGT];    // gtmax branch only
    int t = threadIdx.x;
    if (blockIdx.x < 1024) {
        // ---- conv1 via MFMA: GEMM M=65536, K=48(pad64), N=128 ----
        int l = t & 63;
        int quad = l >> 4;
        int tile = blockIdx.x * 4 + (t >> 6);   // 0..4095
        int m0 = tile * 16;
        int p = m0 + (l & 15);
        int oy = p >> 8, ox = p & 255;
        const float* ib = img + ((size_t)oy * 4 * 1024 + (size_t)ox * 4) * 3;

        bf16x8 a0 = ld_a8(ib, quad * 8);
        bf16x8 a1 = (quad < 2) ? ld_a8(ib, 32 + quad * 8) : (bf16x8){0, 0, 0, 0, 0, 0, 0, 0};

        f32x4 acc[8];
#pragma unroll
        for (int nt = 0; nt < 8; ++nt) acc[nt] = (f32x4){0.0f, 0.0f, 0.0f, 0.0f};
#pragma unroll
        for (int nt = 0; nt < 8; ++nt) {
            bf16x8 b0 = *(const bf16x8*)(g_Wbs + (size_t)(nt * 64 + l) * 8);
            bf16x8 b1 = *(const bf16x8*)(g_Wbs + (size_t)((8 + nt) * 64 + l) * 8);
            acc[nt] = __builtin_amdgcn_mfma_f32_16x16x32_bf16(a0, b0, acc[nt], 0, 0, 0);
            acc[nt] = __builtin_amdgcn_mfma_f32_16x16x32_bf16(a1, b1, acc[nt], 0, 0, 0);
        }

        int n0 = l & 15;
        int mB = m0 + quad * 4;
#pragma unroll
        for (int nt = 0; nt < 8; ++nt) {
            int oc = nt * 16 + n0;
            float bias = bb[oc];
#pragma unroll
            for (int r = 0; r < 4; ++r) {
                g_feats[(size_t)(mB + r) * 128 + oc] = f2b(acc[nt][r] + bias);
            }
        }
    } else {
        // ---- gtmax ----
        int bid = blockIdx.x - 1024;
        int a = bid >> 5;             // 0..8
        int blk = bid & 31;
        float hw, hh;
        type_extent(a, &hw, &hh);
        float m16[KGT];
#pragma unroll
        for (int k = 0; k < KGT; ++k) m16[k] = -1.0f;
        for (int pix = blk * 256 + t; pix < NPIX; pix += 32 * 256) {
            int w = pix / F2, h = pix - w * F2;
            float cx = (float)w * (1.0f / 254.0f);
            float cy = (float)h * (1.0f / 254.0f);
            float x1 = cx - hw, y1 = cy - hh, x2 = cx + hw, y2 = cy + hh;
            bool inside = (x1 >= 0.0f) && (y1 >= 0.0f) && (x2 < 1.0f) && (y2 < 1.0f);
            if (__ballot(inside) == 0ull) continue;   // whole wave outside
            if (inside) {
                float v[KGT];
                iou16(x1, y1, x2, y2, gt, v);
#pragma unroll
                for (int k = 0; k < KGT; ++k) m16[k] = fmaxf(m16[k], v[k]);
            }
        }
#pragma unroll
        for (int k = 0; k < KGT; ++k) {
#pragma unroll
            for (int m = 32; m; m >>= 1) m16[k] = fmaxf(m16[k], __shfl_xor(m16[k], m, 64));
        }
        int lane = t & 63, wv = t >> 6;
        if (lane == 0) {
#pragma unroll
            for (int k = 0; k < KGT; ++k) red[wv][k] = m16[k];
        }
        __syncthreads();
        if (t < KGT) {
            float mx = fmaxf(fmaxf(red[0][t], red[1][t]), fmaxf(red[2][t], red[3][t]));
            unsigned u = __float_as_uint(mx);
            unsigned key = (u & 0x80000000u) ? ~u : (u | 0x80000000u);
            atomicMax(&g_keys[t], key);
        }
    }
}

// ---------------- combined conv via MFMA, 2 M-tiles/wave (proven shape, 505 blocks) ----------------
__global__ __launch_bounds__(256) void k_convC() {
    int t = threadIdx.x;
    int l = t & 63;
    int quad = l >> 4;
    int tile = blockIdx.x * 4 + (t >> 6);
    int m0 = tile * 32;
    int mA0 = min(m0 + (l & 15), NPIX - 1);
    int mA1 = min(m0 + 16 + (l & 15), NPIX - 1);
    int py0 = mA0 / F2, px0 = mA0 - py0 * F2;
    int py1 = mA1 / F2, px1 = mA1 - py1 * F2;

    f32x4 acc[2][3];
#pragma unroll
    for (int h = 0; h < 2; ++h)
#pragma unroll
        for (int nt = 0; nt < 3; ++nt) acc[h][nt] = (f32x4){0.0f, 0.0f, 0.0f, 0.0f};

    int kt = 0;
#pragma unroll
    for (int ky = 0; ky < 3; ++ky) {
#pragma unroll
        for (int kx = 0; kx < 3; ++kx) {
            const unsigned short* ap0 =
                g_feats + ((size_t)(py0 + ky) * 256 + (px0 + kx)) * 128 + quad * 8;
            const unsigned short* ap1 =
                g_feats + ((size_t)(py1 + ky) * 256 + (px1 + kx)) * 128 + quad * 8;
#pragma unroll
            for (int kc = 0; kc < 4; ++kc) {
                bf16x8 a0 = *(const bf16x8*)(ap0 + kc * 32);
                bf16x8 a1 = *(const bf16x8*)(ap1 + kc * 32);
                const unsigned short* bp = g_W2s + (size_t)kt * 1536 + l * 8;
                bf16x8 b0 = *(const bf16x8*)(bp);
                bf16x8 b1 = *(const bf16x8*)(bp + 512);
                bf16x8 b2v = *(const bf16x8*)(bp + 1024);
                acc[0][0] = __builtin_amdgcn_mfma_f32_16x16x32_bf16(a0, b0, acc[0][0], 0, 0, 0);
                acc[0][1] = __builtin_amdgcn_mfma_f32_16x16x32_bf16(a0, b1, acc[0][1], 0, 0, 0);
                acc[0][2] = __builtin_amdgcn_mfma_f32_16x16x32_bf16(a0, b2v, acc[0][2], 0, 0, 0);
                acc[1][0] = __builtin_amdgcn_mfma_f32_16x16x32_bf16(a1, b0, acc[1][0], 0, 0, 0);
                acc[1][1] = __builtin_amdgcn_mfma_f32_16x16x32_bf16(a1, b1, acc[1][1], 0, 0, 0);
                acc[1][2] = __builtin_amdgcn_mfma_f32_16x16x32_bf16(a1, b2v, acc[1][2], 0, 0, 0);
                ++kt;
            }
        }
    }

    int n0 = l & 15;
#pragma unroll
    for (int h = 0; h < 2; ++h) {
        int mB = m0 + h * 16 + quad * 4;
#pragma unroll
        for (int nt = 0; nt < 3; ++nt) {
            int n = nt * 16 + n0;
            if (n >= 45) continue;
            float bias = g_b2[n];
#pragma unroll
            for (int r = 0; r < 4; ++r) {
                int m = mB + r;
                if (m < NPIX) {
                    float vv = acc[h][nt][r] + bias;
                    if (n < 9) g_cls[(size_t)m * 9 + n] = f2b(vv);
                    else       g_reg[(size_t)m * 36 + (n - 9)] = f2b(vv);
                }
            }
        }
    }
}

// ---------------- loss, COMPACT inside-rectangle grid + counter finalize ----------------
__global__ __launch_bounds__(256) void k_loss(const float* __restrict__ gt, unsigned* out,
                                              LossMap lm, int nblocks) {
    __shared__ float red[4][4];
    int t = threadIdx.x;
    int a = 0;
    while (a < 8 && (int)blockIdx.x >= lm.blk0[a + 1]) ++a;
    int idx = ((int)blockIdx.x - lm.blk0[a]) * 256 + t;
    int hsp = lm.hsp[a];
    int w = lm.w0[a] + idx / hsp;
    int h = lm.h0[a] + idx % hsp;
    float sb = 0.0f, ss = 0.0f, sx = 0.0f, sp = 0.0f;
    float hw, hh;
    type_extent(a, &hw, &hh);
    bool inside = false;
    float x1, y1, x2, y2;
    if (w < F2 && h < F2) {
        float cx = (float)w * (1.0f / 254.0f);
        float cy = (float)h * (1.0f / 254.0f);
        x1 = cx - hw; y1 = cy - hh; x2 = cx + hw; y2 = cy + hh;
        inside = (x1 >= 0.0f) && (y1 >= 0.0f) && (x2 < 1.0f) && (y2 < 1.0f);
    }
    if (__ballot(inside) != 0ull) {
        if (inside) {
            int pix = w * F2 + h;
            int n = pix * 9 + a;
            float v[KGT];
            iou16(x1, y1, x2, y2, gt, v);
            float maxi = -1.0f;
            bool best = false;
#pragma unroll
            for (int k = 0; k < KGT; ++k) {
                maxi = fmaxf(maxi, v[k]);
                unsigned e = g_keys[k];
                float gm = __uint_as_float((e & 0x80000000u) ? (e & 0x7FFFFFFFu) : ~e);
                best = best || (v[k] == gm);
            }
            bool ispos = best || (maxi >= 0.5f);
            float c = b2f(g_cls[n]);
            float z = ispos ? -c : c;
            sb = fmaxf(z, 0.0f) + log1pf(expf(-fabsf(z))); // softplus(z)
            ss = 1.0f;
            if (ispos) {
                ushort4 rh = *(const ushort4*)(g_reg + (size_t)n * 4);
                float aa;
                aa = fabsf(b2f(rh.x)); sx += (aa < 1.0f) ? 0.5f * aa * aa : aa - 0.5f;
                aa = fabsf(b2f(rh.y)); sx += (aa < 1.0f) ? 0.5f * aa * aa : aa - 0.5f;
                aa = fabsf(b2f(rh.z)); sx += (aa < 1.0f) ? 0.5f * aa * aa : aa - 0.5f;
                aa = fabsf(b2f(rh.w)); sx += (aa < 1.0f) ? 0.5f * aa * aa : aa - 0.5f;
                sp = 1.0f;
            }
        }
    }
#pragma unroll
    for (int m = 32; m; m >>= 1) {
        sb += __shfl_xor(sb, m, 64);
        ss += __shfl_xor(ss, m, 64);
        sx += __shfl_xor(sx, m, 64);
        sp += __shfl_xor(sp, m, 64);
    }
    int lane = t & 63, wv = t >> 6;
    if (lane == 0) { red[wv][0] = sb; red[wv][1] = ss; red[wv][2] = sx; red[wv][3] = sp; }
    __syncthreads();
    if (t < 4) {
        float s = red[0][t] + red[1][t] + red[2][t] + red[3][t];
        atomicAdd(&g_acc[t], s);
    }
    // barrier drains vmcnt -> this block's g_acc atomics are L2-visible before g_done bump
    __syncthreads();
    if (t == 0) {
        unsigned prev = atomicAdd(&g_done, 1u);
        if (prev == (unsigned)(nblocks - 1)) {   // last block finalizes; atomics read L2 truth
            float a0 = atomicAdd(&g_acc[0], 0.0f);
            float a1 = atomicAdd(&g_acc[1], 0.0f);
            float a2 = atomicAdd(&g_acc[2], 0.0f);
            float a3 = atomicAdd(&g_acc[3], 0.0f);
            float res = a0 / a1 + a2 / a3;
            unsigned lo = (unsigned)f2b(res);
            unsigned hi = __float_as_uint(res) >> 16;
            out[0] = (hi << 16) | lo;
        }
    }
}

extern "C" void kernel_launch(void* const* d_in, const int* in_sizes, int n_in,
                              void* d_out, int out_size, void* d_ws, size_t ws_size,
                              hipStream_t stream) {
    (void)in_sizes; (void)n_in; (void)out_size; (void)d_ws; (void)ws_size;
    const float* image = (const float*)d_in[0];
    const float* gt    = (const float*)d_in[1];
    const float* Wb    = (const float*)d_in[2];
    const float* bb    = (const float*)d_in[3];
    const float* Wi    = (const float*)d_in[4];
    const float* bi    = (const float*)d_in[5];
    const float* Wc    = (const float*)d_in[6];
    const float* bc    = (const float*)d_in[7];
    const float* Wr    = (const float*)d_in[8];
    const float* br    = (const float*)d_in[9];

    // host-side conservative inside-rectangles (±1 pixel slop; per-pixel check stays exact)
    LossMap lm;
    int nb = 0;
    const float RAT[3] = {0.5f, 1.0f, 2.0f};
    const float SCL[3] = {0.2f, 0.4f, 0.7f};
    for (int a = 0; a < 9; ++a) {
        int ri = a / 3, si = a - ri * 3;
        float rs = sqrtf(RAT[ri]);
        float hw = SCL[si] * rs * 0.5f;
        float hh = SCL[si] / rs * 0.5f;
        int wa0 = (int)floorf(254.0f * hw) - 1; if (wa0 < 0) wa0 = 0;
        int wa1 = (int)ceilf(254.0f * (1.0f - hw)) + 1; if (wa1 > 253) wa1 = 253;
        int ha0 = (int)floorf(254.0f * hh) - 1; if (ha0 < 0) ha0 = 0;
        int ha1 = (int)ceilf(254.0f * (1.0f - hh)) + 1; if (ha1 > 253) ha1 = 253;
        int wspan = wa1 - wa0 + 1, hspan = ha1 - ha0 + 1;
        lm.w0[a] = wa0; lm.h0[a] = ha0; lm.hsp[a] = hspan;
        lm.blk0[a] = nb;
        nb += (wspan * hspan + 255) / 256;
    }
    lm.blk0[9] = nb;

    k_w2     <<<292, 256, 0, stream>>>(Wi, bi, Wc, bc, Wr, br, Wb, (unsigned*)d_out);
    k_conv1gt<<<1312, 256, 0, stream>>>(image, bb, gt);
    k_convC  <<<505, 256, 0, stream>>>();
    k_loss   <<<nb, 256, 0, stream>>>(gt, (unsigned*)d_out, lm, nb);
}

// Round 19
// 149.739 us; speedup vs baseline: 1.2657x; 1.0245x over previous
//
#include <hip/hip_runtime.h>

// ---------------- problem constants ----------------
#define F2      254
#define NPIX    (F2 * F2)        // 64516 conv2 output pixels
#define NANCH   (NPIX * 9)       // 580644 anchors
#define KGT     16
#define GWC     (1.0f / 1024.0f) // gw == gh == 1/IMG

typedef __attribute__((ext_vector_type(8))) short bf16x8;
typedef __attribute__((ext_vector_type(4))) float f32x4;

// loss compact-grid map (host-computed, passed by value)
struct LossMap {
    int w0[9], h0[9], hsp[9], blk0[10];
};

// ---------------- static device storage ----------------
__device__ unsigned short g_feats[256 * 256 * 128];  // conv1 out, bf16, 16.78 MB
__device__ unsigned short g_cls[NPIX * 9];           // cls logits bf16
__device__ unsigned short g_reg[NPIX * 36];          // reg preds bf16
__device__ unsigned short g_W2s[36 * 3 * 64 * 8];    // combined conv2 weights, bf16, MFMA-B swizzled
__device__ unsigned short g_Wbs[2 * 8 * 64 * 8];     // conv1 weights, bf16, MFMA-B swizzled (K pad 48->64)
__device__ float          g_b2[48];
__device__ float          g_acc[4];                  // bce_sum, sel_cnt, box_sum, pos_cnt
__device__ unsigned       g_keys[KGT];               // monotone-encoded gt-max
__device__ unsigned       g_done;                    // loss completion counter

__device__ __forceinline__ float b2f(unsigned short h) {
    return __uint_as_float(((unsigned)h) << 16);
}
__device__ __forceinline__ unsigned short f2b(float f) {
    unsigned u = __float_as_uint(f);
    unsigned r = (u + 0x7FFFu + ((u >> 16) & 1u)) >> 16;
    return (unsigned short)r;
}

// ---------------- shared IoU16: ONE inlined expression tree -> bit-exact across callers ----------------
__device__ __forceinline__ void iou16(float x1, float y1, float x2, float y2,
                                      const float* __restrict__ gt, float* __restrict__ v) {
    float s1 = (x2 - x1 + GWC) * (y2 - y1 + GWC);
#pragma unroll
    for (int k = 0; k < KGT; ++k) {
        float gx1 = gt[k * 4 + 0], gy1 = gt[k * 4 + 1];
        float gx2 = gt[k * 4 + 2], gy2 = gt[k * 4 + 3];
        float s2 = (gx2 - gx1 + GWC) * (gy2 - gy1 + GWC);
        float xa = fmaxf(x1, gx1), ya = fmaxf(y1, gy1);
        float xb = fminf(x2, gx2), yb = fminf(y2, gy2);
        float iw = fmaxf(xb - xa + GWC, 0.0f);
        float ih = fmaxf(yb - ya + GWC, 0.0f);
        float inter = iw * ih;
        v[k] = inter / (s1 + s2 - inter);
    }
}

// per-type half extents (uniform within a type-major block)
__device__ __forceinline__ void type_extent(int a, float* hw, float* hh) {
    int ri = a / 3, si = a - ri * 3;
    float rat = (ri == 0) ? 0.5f : (ri == 1) ? 1.0f : 2.0f;
    float scl = (si == 0) ? 0.2f : (si == 1) ? 0.4f : 0.7f;
    float rs = sqrtf(rat);
    *hw = scl * rs * 0.5f;
    *hh = scl / rs * 0.5f;
}

// ---------------- W2/Wb precombine + swizzle (+ merged init) — proven, OWN LAUNCH ----------------
__global__ __launch_bounds__(256) void k_w2(const float* __restrict__ Wi,
                                            const float* __restrict__ bi,
                                            const float* __restrict__ Wc,
                                            const float* __restrict__ bc,
                                            const float* __restrict__ Wr,
                                            const float* __restrict__ br,
                                            const float* __restrict__ Wb,
                                            unsigned* out) {
    int t = threadIdx.x;
    int b = blockIdx.x;
    if (b >= 288) {                  // Wb swizzle: 4 blocks x 256 thr x 8 entries
        int e = (b - 288) * 256 + t; // (kt,nt,l)
        int kt = e >> 9, nt = (e >> 6) & 7, l = e & 63;
        unsigned short w8[8];
#pragma unroll
        for (int j = 0; j < 8; ++j) {
            int k = kt * 32 + ((l >> 4) * 8) + j;
            int oc = nt * 16 + (l & 15);
            w8[j] = (k < 48) ? f2b(Wb[(size_t)k * 128 + oc]) : (unsigned short)0;
        }
        *(ulonglong2*)(g_Wbs + (size_t)e * 8) = *(ulonglong2*)w8;
        return;
    }
    __shared__ float wcr[256][48];   // 48 KB
    if (b == 0) {                    // merged init (resets ALL cross-call state every call)
        if (t < 4) g_acc[t] = 0.0f;
        if (t >= 4 && t < 4 + KGT) g_keys[t - 4] = 0x407FFFFFu; // enc(-1.0f)
        if (t == 32) out[0] = 0x3F803F80u;
        if (t == 33) g_done = 0u;
    }
    for (int i = t; i < 2304; i += 256) wcr[i / 9][i % 9] = Wc[i];
    for (int i = t; i < 9216; i += 256) wcr[i / 36][9 + i % 36] = Wr[i];
    for (int i = t; i < 768; i += 256) wcr[i / 3][45 + i % 3] = 0.0f;
    __syncthreads();

    int wave = __builtin_amdgcn_readfirstlane(t >> 6);
    int lane = t & 63;
    int k = b * 4 + wave;            // 0..1151
    int o = min(lane, 47);
    const float* wik = Wi + (size_t)k * 256;
    float acc = 0.0f;
#pragma unroll 8
    for (int oc = 0; oc < 256; ++oc)
        acc = fmaf(wik[oc], wcr[oc][o], acc);

    if (lane < 48) {
        int kt = k >> 5, r5 = k & 31, j = r5 & 7, lhi = r5 >> 3;
        int nt = o >> 4, llo = o & 15, l = lhi * 16 + llo;
        g_W2s[(size_t)((kt * 3 + nt) * 64 + l) * 8 + j] = f2b(acc);
    }
    if (b == 0 && t < 48) {
        float a2 = (t < 9) ? bc[t] : ((t < 45) ? br[t - 9] : 0.0f);
        for (int oc = 0; oc < 256; ++oc) a2 = fmaf(bi[oc], wcr[oc][t], a2);
        g_b2[t] = a2;
    }
}

// helper: load 8 consecutive im2col k-values (k-order = r*12+q) of one pixel as bf16x8
__device__ __forceinline__ bf16x8 ld_a8(const float* ib, int kbase) {
    int r0 = kbase / 12, q0 = kbase - r0 * 12;
    unsigned short a8[8];
    float4 f0 = *(const float4*)(ib + (size_t)r0 * 3072 + q0);
    int k4 = kbase + 4;
    int r1 = k4 / 12, q1 = k4 - r1 * 12;
    float4 f1 = *(const float4*)(ib + (size_t)r1 * 3072 + q1);
    a8[0] = f2b(f0.x); a8[1] = f2b(f0.y); a8[2] = f2b(f0.z); a8[3] = f2b(f0.w);
    a8[4] = f2b(f1.x); a8[5] = f2b(f1.y); a8[6] = f2b(f1.z); a8[7] = f2b(f1.w);
    return *(bf16x8*)a8;
}

// ---------------- MERGED conv1(MFMA) + gtmax — consumes g_Wbs across a KERNEL BOUNDARY ----------------
__global__ __launch_bounds__(256) void k_conv1gt(const float* __restrict__ img,
                                                 const float* __restrict__ bb,
                                                 const float* __restrict__ gt) {
    __shared__ float red[4][KGT];    // gtmax branch only
    int t = threadIdx.x;
    if (blockIdx.x < 1024) {
        // ---- conv1 via MFMA: GEMM M=65536, K=48(pad64), N=128 ----
        int l = t & 63;
        int quad = l >> 4;
        int tile = blockIdx.x * 4 + (t >> 6);   // 0..4095
        int m0 = tile * 16;
        int p = m0 + (l & 15);
        int oy = p >> 8, ox = p & 255;
        const float* ib = img + ((size_t)oy * 4 * 1024 + (size_t)ox * 4) * 3;

        bf16x8 a0 = ld_a8(ib, quad * 8);
        bf16x8 a1 = (quad < 2) ? ld_a8(ib, 32 + quad * 8) : (bf16x8){0, 0, 0, 0, 0, 0, 0, 0};

        f32x4 acc[8];
#pragma unroll
        for (int nt = 0; nt < 8; ++nt) acc[nt] = (f32x4){0.0f, 0.0f, 0.0f, 0.0f};
#pragma unroll
        for (int nt = 0; nt < 8; ++nt) {
            bf16x8 b0 = *(const bf16x8*)(g_Wbs + (size_t)(nt * 64 + l) * 8);
            bf16x8 b1 = *(const bf16x8*)(g_Wbs + (size_t)((8 + nt) * 64 + l) * 8);
            acc[nt] = __builtin_amdgcn_mfma_f32_16x16x32_bf16(a0, b0, acc[nt], 0, 0, 0);
            acc[nt] = __builtin_amdgcn_mfma_f32_16x16x32_bf16(a1, b1, acc[nt], 0, 0, 0);
        }

        int n0 = l & 15;
        int mB = m0 + quad * 4;
#pragma unroll
        for (int nt = 0; nt < 8; ++nt) {
            int oc = nt * 16 + n0;
            float bias = bb[oc];
#pragma unroll
            for (int r = 0; r < 4; ++r) {
                g_feats[(size_t)(mB + r) * 128 + oc] = f2b(acc[nt][r] + bias);
            }
        }
    } else {
        // ---- gtmax ----
        int bid = blockIdx.x - 1024;
        int a = bid >> 5;             // 0..8
        int blk = bid & 31;
        float hw, hh;
        type_extent(a, &hw, &hh);
        float m16[KGT];
#pragma unroll
        for (int k = 0; k < KGT; ++k) m16[k] = -1.0f;
        for (int pix = blk * 256 + t; pix < NPIX; pix += 32 * 256) {
            int w = pix / F2, h = pix - w * F2;
            float cx = (float)w * (1.0f / 254.0f);
            float cy = (float)h * (1.0f / 254.0f);
            float x1 = cx - hw, y1 = cy - hh, x2 = cx + hw, y2 = cy + hh;
            bool inside = (x1 >= 0.0f) && (y1 >= 0.0f) && (x2 < 1.0f) && (y2 < 1.0f);
            if (__ballot(inside) == 0ull) continue;   // whole wave outside
            if (inside) {
                float v[KGT];
                iou16(x1, y1, x2, y2, gt, v);
#pragma unroll
                for (int k = 0; k < KGT; ++k) m16[k] = fmaxf(m16[k], v[k]);
            }
        }
#pragma unroll
        for (int k = 0; k < KGT; ++k) {
#pragma unroll
            for (int m = 32; m; m >>= 1) m16[k] = fmaxf(m16[k], __shfl_xor(m16[k], m, 64));
        }
        int lane = t & 63, wv = t >> 6;
        if (lane == 0) {
#pragma unroll
            for (int k = 0; k < KGT; ++k) red[wv][k] = m16[k];
        }
        __syncthreads();
        if (t < KGT) {
            float mx = fmaxf(fmaxf(red[0][t], red[1][t]), fmaxf(red[2][t], red[3][t]));
            unsigned u = __float_as_uint(mx);
            unsigned key = (u & 0x80000000u) ? ~u : (u | 0x80000000u);
            atomicMax(&g_keys[t], key);
        }
    }
}

// ---------------- combined conv via MFMA, 2 M-tiles/wave + LDS-staged B ----------------
// B fragments are lane-identical across the 4 waves -> stage g_W2s in LDS once per block,
// chunked 12 kt (36 KB), single-buffered. Arithmetic byte-identical to the global-B version.
__global__ __launch_bounds__(256) void k_convC() {
    __shared__ unsigned short Bs[12 * 1536];   // 36 KB: 12 kt x (3 nt x 64 lane x 8)
    int t = threadIdx.x;
    int l = t & 63;
    int quad = l >> 4;
    int tile = blockIdx.x * 4 + (t >> 6);
    int m0 = tile * 32;
    int mA0 = min(m0 + (l & 15), NPIX - 1);
    int mA1 = min(m0 + 16 + (l & 15), NPIX - 1);
    int py0 = mA0 / F2, px0 = mA0 - py0 * F2;
    int py1 = mA1 / F2, px1 = mA1 - py1 * F2;

    f32x4 acc[2][3];
#pragma unroll
    for (int h = 0; h < 2; ++h)
#pragma unroll
        for (int nt = 0; nt < 3; ++nt) acc[h][nt] = (f32x4){0.0f, 0.0f, 0.0f, 0.0f};

    for (int c = 0; c < 3; ++c) {              // chunk = 12 kt
        __syncthreads();
        {   // cooperative stage: 18432 shorts = 2304 uint4 = 9 x 256
            const uint4* src = (const uint4*)(g_W2s + (size_t)c * 18432);
            uint4* dst = (uint4*)Bs;
#pragma unroll
            for (int j = 0; j < 9; ++j) dst[t + 256 * j] = src[t + 256 * j];
        }
        __syncthreads();
#pragma unroll
        for (int i = 0; i < 12; ++i) {
            int kt = c * 12 + i;
            int pos = kt >> 2, kc = kt & 3;
            int ky = pos / 3, kx = pos - ky * 3;
            const unsigned short* ap0 =
                g_feats + ((size_t)(py0 + ky) * 256 + (px0 + kx)) * 128 + quad * 8 + kc * 32;
            const unsigned short* ap1 =
                g_feats + ((size_t)(py1 + ky) * 256 + (px1 + kx)) * 128 + quad * 8 + kc * 32;
            bf16x8 a0 = *(const bf16x8*)ap0;
            bf16x8 a1 = *(const bf16x8*)ap1;
            const unsigned short* bp = Bs + (size_t)i * 1536 + l * 8;
            bf16x8 b0 = *(const bf16x8*)(bp);
            bf16x8 b1 = *(const bf16x8*)(bp + 512);
            bf16x8 b2v = *(const bf16x8*)(bp + 1024);
            acc[0][0] = __builtin_amdgcn_mfma_f32_16x16x32_bf16(a0, b0, acc[0][0], 0, 0, 0);
            acc[0][1] = __builtin_amdgcn_mfma_f32_16x16x32_bf16(a0, b1, acc[0][1], 0, 0, 0);
            acc[0][2] = __builtin_amdgcn_mfma_f32_16x16x32_bf16(a0, b2v, acc[0][2], 0, 0, 0);
            acc[1][0] = __builtin_amdgcn_mfma_f32_16x16x32_bf16(a1, b0, acc[1][0], 0, 0, 0);
            acc[1][1] = __builtin_amdgcn_mfma_f32_16x16x32_bf16(a1, b1, acc[1][1], 0, 0, 0);
            acc[1][2] = __builtin_amdgcn_mfma_f32_16x16x32_bf16(a1, b2v, acc[1][2], 0, 0, 0);
        }
    }

    int n0 = l & 15;
#pragma unroll
    for (int h = 0; h < 2; ++h) {
        int mB = m0 + h * 16 + quad * 4;
#pragma unroll
        for (int nt = 0; nt < 3; ++nt) {
            int n = nt * 16 + n0;
            if (n >= 45) continue;
            float bias = g_b2[n];
#pragma unroll
            for (int r = 0; r < 4; ++r) {
                int m = mB + r;
                if (m < NPIX) {
                    float vv = acc[h][nt][r] + bias;
                    if (n < 9) g_cls[(size_t)m * 9 + n] = f2b(vv);
                    else       g_reg[(size_t)m * 36 + (n - 9)] = f2b(vv);
                }
            }
        }
    }
}

// ---------------- loss, COMPACT inside-rectangle grid + counter finalize ----------------
__global__ __launch_bounds__(256) void k_loss(const float* __restrict__ gt, unsigned* out,
                                              LossMap lm, int nblocks) {
    __shared__ float red[4][4];
    int t = threadIdx.x;
    int a = 0;
    while (a < 8 && (int)blockIdx.x >= lm.blk0[a + 1]) ++a;
    int idx = ((int)blockIdx.x - lm.blk0[a]) * 256 + t;
    int hsp = lm.hsp[a];
    int w = lm.w0[a] + idx / hsp;
    int h = lm.h0[a] + idx % hsp;
    float sb = 0.0f, ss = 0.0f, sx = 0.0f, sp = 0.0f;
    float hw, hh;
    type_extent(a, &hw, &hh);
    bool inside = false;
    float x1, y1, x2, y2;
    if (w < F2 && h < F2) {
        float cx = (float)w * (1.0f / 254.0f);
        float cy = (float)h * (1.0f / 254.0f);
        x1 = cx - hw; y1 = cy - hh; x2 = cx + hw; y2 = cy + hh;
        inside = (x1 >= 0.0f) && (y1 >= 0.0f) && (x2 < 1.0f) && (y2 < 1.0f);
    }
    if (__ballot(inside) != 0ull) {
        if (inside) {
            int pix = w * F2 + h;
            int n = pix * 9 + a;
            float v[KGT];
            iou16(x1, y1, x2, y2, gt, v);
            float maxi = -1.0f;
            bool best = false;
#pragma unroll
            for (int k = 0; k < KGT; ++k) {
                maxi = fmaxf(maxi, v[k]);
                unsigned e = g_keys[k];
                float gm = __uint_as_float((e & 0x80000000u) ? (e & 0x7FFFFFFFu) : ~e);
                best = best || (v[k] == gm);
            }
            bool ispos = best || (maxi >= 0.5f);
            float c = b2f(g_cls[n]);
            float z = ispos ? -c : c;
            sb = fmaxf(z, 0.0f) + log1pf(expf(-fabsf(z))); // softplus(z)
            ss = 1.0f;
            if (ispos) {
                ushort4 rh = *(const ushort4*)(g_reg + (size_t)n * 4);
                float aa;
                aa = fabsf(b2f(rh.x)); sx += (aa < 1.0f) ? 0.5f * aa * aa : aa - 0.5f;
                aa = fabsf(b2f(rh.y)); sx += (aa < 1.0f) ? 0.5f * aa * aa : aa - 0.5f;
                aa = fabsf(b2f(rh.z)); sx += (aa < 1.0f) ? 0.5f * aa * aa : aa - 0.5f;
                aa = fabsf(b2f(rh.w)); sx += (aa < 1.0f) ? 0.5f * aa * aa : aa - 0.5f;
                sp = 1.0f;
            }
        }
    }
#pragma unroll
    for (int m = 32; m; m >>= 1) {
        sb += __shfl_xor(sb, m, 64);
        ss += __shfl_xor(ss, m, 64);
        sx += __shfl_xor(sx, m, 64);
        sp += __shfl_xor(sp, m, 64);
    }
    int lane = t & 63, wv = t >> 6;
    if (lane == 0) { red[wv][0] = sb; red[wv][1] = ss; red[wv][2] = sx; red[wv][3] = sp; }
    __syncthreads();
    if (t < 4) {
        float s = red[0][t] + red[1][t] + red[2][t] + red[3][t];
        atomicAdd(&g_acc[t], s);
    }
    // barrier drains vmcnt -> this block's g_acc atomics are L2-visible before g_done bump
    __syncthreads();
    if (t == 0) {
        unsigned prev = atomicAdd(&g_done, 1u);
        if (prev == (unsigned)(nblocks - 1)) {   // last block finalizes; atomics read L2 truth
            float a0 = atomicAdd(&g_acc[0], 0.0f);
            float a1 = atomicAdd(&g_acc[1], 0.0f);
            float a2 = atomicAdd(&g_acc[2], 0.0f);
            float a3 = atomicAdd(&g_acc[3], 0.0f);
            float res = a0 / a1 + a2 / a3;
            unsigned lo = (unsigned)f2b(res);
            unsigned hi = __float_as_uint(res) >> 16;
            out[0] = (hi << 16) | lo;
        }
    }
}

extern "C" void kernel_launch(void* const* d_in, const int* in_sizes, int n_in,
                              void* d_out, int out_size, void* d_ws, size_t ws_size,
                              hipStream_t stream) {
    (void)in_sizes; (void)n_in; (void)out_size; (void)d_ws; (void)ws_size;
    const float* image = (const float*)d_in[0];
    const float* gt    = (const float*)d_in[1];
    const float* Wb    = (const float*)d_in[2];
    const float* bb    = (const float*)d_in[3];
    const float* Wi    = (const float*)d_in[4];
    const float* bi    = (const float*)d_in[5];
    const float* Wc    = (const float*)d_in[6];
    const float* bc    = (const float*)d_in[7];
    const float* Wr    = (const float*)d_in[8];
    const float* br    = (const float*)d_in[9];

    // host-side conservative inside-rectangles (±1 pixel slop; per-pixel check stays exact)
    LossMap lm;
    int nb = 0;
    const float RAT[3] = {0.5f, 1.0f, 2.0f};
    const float SCL[3] = {0.2f, 0.4f, 0.7f};
    for (int a = 0; a < 9; ++a) {
        int ri = a / 3, si = a - ri * 3;
        float rs = sqrtf(RAT[ri]);
        float hw = SCL[si] * rs * 0.5f;
        float hh = SCL[si] / rs * 0.5f;
        int wa0 = (int)floorf(254.0f * hw) - 1; if (wa0 < 0) wa0 = 0;
        int wa1 = (int)ceilf(254.0f * (1.0f - hw)) + 1; if (wa1 > 253) wa1 = 253;
        int ha0 = (int)floorf(254.0f * hh) - 1; if (ha0 < 0) ha0 = 0;
        int ha1 = (int)ceilf(254.0f * (1.0f - hh)) + 1; if (ha1 > 253) ha1 = 253;
        int wspan = wa1 - wa0 + 1, hspan = ha1 - ha0 + 1;
        lm.w0[a] = wa0; lm.h0[a] = ha0; lm.hsp[a] = hspan;
        lm.blk0[a] = nb;
        nb += (wspan * hspan + 255) / 256;
    }
    lm.blk0[9] = nb;

    k_w2     <<<292, 256, 0, stream>>>(Wi, bi, Wc, bc, Wr, br, Wb, (unsigned*)d_out);
    k_conv1gt<<<1312, 256, 0, stream>>>(image, bb, gt);
    k_convC  <<<505, 256, 0, stream>>>();
    k_loss   <<<nb, 256, 0, stream>>>(gt, (unsigned*)d_out, lm, nb);
}